// Round 3
// baseline (238.416 us; speedup 1.0000x reference)
//
#include <hip/hip_runtime.h>

// TAM fused kernel round 3: barrier-free wave-per-sample design.
// C=12, T=10, H*W=28, K=3. One 64-thread block (= one wave) per sample.
// All cross-lane comm is intra-wave via LDS with wave-level waitcnt sync
// (no __syncthreads -> no vmcnt(0) drains -> VMEM pipe never forced idle).

#define CC 12
#define TT 10
#define HWS 28
#define SAMPLE 3360      // floats per sample
#define SAMPLE4 840      // f4 per sample
#define EPSF 1e-5f

typedef float f4 __attribute__((ext_vector_type(4)));

// Wave-level LDS producer->consumer sync (same wave, lockstep):
// lgkmcnt(0) ensures LDS ops landed; "memory" stops reg-caching across;
// sched_barrier(0) stops hipcc hoisting dependent ops past the asm (rule #18).
#define WSYNC() do { asm volatile("s_waitcnt lgkmcnt(0)" ::: "memory"); \
                     __builtin_amdgcn_sched_barrier(0); } while (0)

__global__ __launch_bounds__(64) void tam_kernel(
    const float* __restrict__ x,
    const float* __restrict__ w_g1,
    const float* __restrict__ g1_gamma, const float* __restrict__ g1_beta,
    const float* __restrict__ g1_mean,  const float* __restrict__ g1_var,
    const float* __restrict__ w_g2,
    const float* __restrict__ w_l1,
    const float* __restrict__ l1_gamma, const float* __restrict__ l1_beta,
    const float* __restrict__ l1_mean,  const float* __restrict__ l1_var,
    const float* __restrict__ w_l2,
    float* __restrict__ out)
{
    __shared__ f4    sx4[SAMPLE4];   // x in input order [c][t][s4]
    __shared__ float spool[CC * TT]; // pooled[c][t]
    __shared__ float sz[CC * 2 * TT];// G hidden
    __shared__ float sa1[3 * TT];    // L hidden
    __shared__ f4    skern[CC];      // softmax kernel {k0,k1,k2,0}
    __shared__ float sact[CC * TT];  // sigmoid gate
    __shared__ f4    sw4[CC * TT];   // fused conv coefs per (c,t): {w0,w1,w2,0}

    const int n    = blockIdx.x;
    const int lane = threadIdx.x;    // 0..63 (one wave)

    // ---- phase 1: stage sample into LDS (coalesced 1KB/instr, NT) ----
    const f4* xg = reinterpret_cast<const f4*>(x + (size_t)n * SAMPLE);
    f4 r[13];
    #pragma unroll
    for (int k = 0; k < 13; ++k)
        r[k] = __builtin_nontemporal_load(xg + k * 64 + lane);
    f4 rt = (f4)0.f;
    if (lane < 8) rt = __builtin_nontemporal_load(xg + 832 + lane);
    #pragma unroll
    for (int k = 0; k < 13; ++k) sx4[k * 64 + lane] = r[k];
    if (lane < 8) sx4[832 + lane] = rt;
    WSYNC();

    // ---- phase 2: spatial mean -> spool[c*10+t] (120 rows, 2/lane) ----
    #pragma unroll
    for (int rr = 0; rr < 2; ++rr) {
        const int row = lane + rr * 64;
        if (row < CC * TT) {
            const f4* rp = sx4 + row * 7;
            f4 a = rp[0];
            #pragma unroll
            for (int i = 1; i < 7; ++i) a += rp[i];
            spool[row] = (a.x + a.y + a.z + a.w) * (1.0f / 28.0f);
        }
    }
    WSYNC();

    // ---- phase 3: G hidden z (240 tasks) + L conv1 (30 tasks) ----
    #pragma unroll
    for (int q = 0; q < 5; ++q) {
        const int task = lane + q * 64;
        if (task < 240) {
            const int c = task / 20, j = task % 20;
            float s = 0.f;
            #pragma unroll
            for (int t = 0; t < TT; ++t) s += spool[c * TT + t] * w_g1[j * TT + t];
            s = (s - g1_mean[j]) * rsqrtf(g1_var[j] + EPSF) * g1_gamma[j] + g1_beta[j];
            sz[task] = fmaxf(s, 0.f);
        } else if (task < 270) {
            const int e = task - 240;
            const int m = e / TT, t = e % TT;
            float s = 0.f;
            #pragma unroll
            for (int c = 0; c < CC; ++c) {
                #pragma unroll
                for (int k = 0; k < 3; ++k) {
                    const int t2 = t + k - 1;
                    if (t2 >= 0 && t2 < TT)
                        s += spool[c * TT + t2] * w_l1[(m * CC + c) * 3 + k];
                }
            }
            s = (s - l1_mean[m]) * rsqrtf(l1_var[m] + EPSF) * l1_gamma[m] + l1_beta[m];
            sa1[e] = fmaxf(s, 0.f);
        }
    }
    WSYNC();

    // ---- phase 4: G scores+softmax (12 lanes) + L conv2+sigmoid (120) ----
    if (lane < CC) {
        const int c = lane;
        float sc0 = 0.f, sc1 = 0.f, sc2 = 0.f;
        #pragma unroll
        for (int j = 0; j < 20; ++j) {
            const float zj = sz[c * 20 + j];
            sc0 += zj * w_g2[j];
            sc1 += zj * w_g2[20 + j];
            sc2 += zj * w_g2[40 + j];
        }
        const float mx = fmaxf(sc0, fmaxf(sc1, sc2));
        const float e0 = __expf(sc0 - mx), e1 = __expf(sc1 - mx), e2 = __expf(sc2 - mx);
        const float ri = 1.0f / (e0 + e1 + e2);
        f4 kk; kk.x = e0 * ri; kk.y = e1 * ri; kk.z = e2 * ri; kk.w = 0.f;
        skern[c] = kk;
    }
    #pragma unroll
    for (int q = 0; q < 2; ++q) {
        const int task = lane + q * 64;
        if (task < CC * TT) {
            const int c = task / TT, t = task % TT;
            float s = 0.f;
            #pragma unroll
            for (int m = 0; m < 3; ++m) s += sa1[m * TT + t] * w_l2[c * 3 + m];
            sact[task] = 1.0f / (1.0f + __expf(-s));
        }
    }
    WSYNC();

    // ---- phase 5: fused coefs sw4[c][t] = {k0*act[t-1], k1*act[t], k2*act[t+1]} ----
    #pragma unroll
    for (int q = 0; q < 2; ++q) {
        const int task = lane + q * 64;
        if (task < CC * TT) {
            const int c = task / TT, t = task % TT;
            const f4 kk = skern[c];
            f4 w;
            w.x = (t > 0) ? kk.x * sact[c * TT + t - 1] : 0.f;
            w.y = kk.y * sact[c * TT + t];
            w.z = (t < 9) ? kk.z * sact[c * TT + t + 1] : 0.f;
            w.w = 0.f;
            sw4[task] = w;
        }
    }
    WSYNC();

    // ---- phase 6: temporal conv + transposed coalesced store ----
    // out f4 index vo = t*84 + c*7 + s4; x f4 index = c*70 + t'*7 + s4.
    f4* og = reinterpret_cast<f4*>(out + (size_t)n * SAMPLE);
    #pragma unroll
    for (int k = 0; k < 14; ++k) {
        const int vo = lane + k * 64;
        if (k < 13 || lane < 8) {
            const int t   = vo / 84;
            const int rem = vo % 84;
            const int c   = rem / 7;
            const int s4  = rem % 7;
            const f4 w = sw4[c * TT + t];
            const int base = c * 70 + s4;
            const int tm = (t > 0) ? t - 1 : 0;
            const int tp = (t < 9) ? t + 1 : 9;
            const f4 x0 = sx4[base + tm * 7];
            const f4 x1 = sx4[base + t * 7];
            const f4 x2 = sx4[base + tp * 7];
            const f4 acc = w.x * x0 + w.y * x1 + w.z * x2;
            og[vo] = acc;
        }
    }
}

extern "C" void kernel_launch(void* const* d_in, const int* in_sizes, int n_in,
                              void* d_out, int out_size, void* d_ws, size_t ws_size,
                              hipStream_t stream) {
    (void)n_in; (void)out_size; (void)d_ws; (void)ws_size;
    const float* x        = (const float*)d_in[0];
    const float* w_g1     = (const float*)d_in[1];
    const float* g1_gamma = (const float*)d_in[2];
    const float* g1_beta  = (const float*)d_in[3];
    const float* g1_mean  = (const float*)d_in[4];
    const float* g1_var   = (const float*)d_in[5];
    const float* w_g2     = (const float*)d_in[6];
    const float* w_l1     = (const float*)d_in[7];
    const float* l1_gamma = (const float*)d_in[8];
    const float* l1_beta  = (const float*)d_in[9];
    const float* l1_mean  = (const float*)d_in[10];
    const float* l1_var   = (const float*)d_in[11];
    const float* w_l2     = (const float*)d_in[12];
    float* out = (float*)d_out;

    const int n_total = in_sizes[0] / SAMPLE;  // 32768
    tam_kernel<<<n_total, 64, 0, stream>>>(
        x, w_g1, g1_gamma, g1_beta, g1_mean, g1_var, w_g2,
        w_l1, l1_gamma, l1_beta, l1_mean, l1_var, w_l2, out);
}